// Round 2
// baseline (635.126 us; speedup 1.0000x reference)
//
#include <hip/hip_runtime.h>

// ThreeStateExplorer: B=256 particles, T=100k steps.
//   k[t]   = inclusive cumsum(states==2)
//   vel[t] = (states[t]==2 ? 0 : e0s[b,k[t]] * (states[t]==0 ? sp0 : sp1))
//   X[t]   = x0 + DT * cumsum(vel)
//
// R4: 3-kernel partitioned scan. R3 taught us: (a) lgkm-only barriers race under
// graph replay (reverted — __syncthreads() everywhere), (b) barrier drain is NOT
// the bottleneck (590 us with or without) => latency-bound at 0.9 TB/s eff BW.
// Fix: 4 partitions/particle, 3 stream-ordered kernels (count -> vel totals ->
// positions). 1024 blocks x 256 thr = 4 blocks/CU overlap each other's stalls.
// No atomics/flags: replay-safe, deterministic. ws = B*4*16 bytes (16 KB).

#define NT    256           // threads per block (4 waves)
#define IPT   8             // elements per thread per chunk
#define CHUNK (NT * IPT)    // 2048
#define NW    (NT / 64)     // 4 waves
#define NPART 4             // partitions per particle

__device__ __forceinline__ void load_states(const int* __restrict__ st, int lim,
                                            int e0i, int out[IPT]) {
    if (e0i + IPT <= lim) {
        int4 a = *(const int4*)(st + e0i);
        int4 b = *(const int4*)(st + e0i + 4);
        out[0] = a.x; out[1] = a.y; out[2] = a.z; out[3] = a.w;
        out[4] = b.x; out[5] = b.y; out[6] = b.z; out[7] = b.w;
    } else {
        #pragma unroll
        for (int j = 0; j < IPT; ++j)
            out[j] = (e0i + j < lim) ? st[e0i + j] : 3;  // sentinel: vel=0, no tumble
    }
}

// ---------------- K1: per-partition tumble counts ----------------
__global__ __launch_bounds__(NT)
void count_kernel(const int* __restrict__ states, int T, int psz, int npart,
                  int* __restrict__ cnt)
{
    const int blk  = blockIdx.x;
    const int b    = blk / npart;
    const int p    = blk - b * npart;
    const int tid  = threadIdx.x;
    const int lane = tid & 63;
    const int wid  = tid >> 6;

    const int* st = states + (size_t)b * T;
    const int pstart = p * psz;
    int pend = pstart + psz; if (pend > T) pend = T;

    __shared__ int s_w[NW];

    int c = 0;
    for (int base = pstart; base < pend; base += CHUNK) {
        int cur[IPT];
        load_states(st, pend, base + tid * IPT, cur);
        #pragma unroll
        for (int j = 0; j < IPT; ++j) c += (cur[j] == 2);
    }
    #pragma unroll
    for (int d = 32; d > 0; d >>= 1) c += __shfl_down(c, d, 64);
    if (lane == 0) s_w[wid] = c;
    __syncthreads();
    if (tid == 0) {
        int t = 0;
        #pragma unroll
        for (int w = 0; w < NW; ++w) t += s_w[w];
        cnt[blk] = t;   // written every launch before anyone reads: replay-safe
    }
}

// ---------------- K2: per-partition velocity-sum totals ----------------
__global__ __launch_bounds__(NT)
void velsum_kernel(const int*   __restrict__ states,
                   const float* __restrict__ e0s,
                   const float* __restrict__ sp0v,
                   const float* __restrict__ sp1v,
                   int T, int psz, int npart,
                   const int*   __restrict__ cnt,
                   float*       __restrict__ velws)
{
    const int blk  = blockIdx.x;
    const int b    = blk / npart;
    const int p    = blk - b * npart;
    const int tid  = threadIdx.x;
    const int lane = tid & 63;
    const int wid  = tid >> 6;

    const int*   st = states + (size_t)b * T;
    const float* er = e0s    + (size_t)b * (T + 1) * 3;
    const float sp0 = sp0v[b], sp1 = sp1v[b];
    const int pstart = p * psz;
    int pend = pstart + psz; if (pend > T) pend = T;

    __shared__ int   s_wi[2][NW];   // double-buffered: 1 barrier per sub-chunk
    __shared__ float s_wf[NW][3];

    int kc = 0;
    for (int q = 0; q < p; ++q) kc += cnt[b * npart + q];

    float vx = 0.f, vy = 0.f, vz = 0.f;
    int par = 0;
    for (int base = pstart; base < pend; base += CHUNK, par ^= 1) {
        int cur[IPT];
        load_states(st, pend, base + tid * IPT, cur);

        int c = 0;
        #pragma unroll
        for (int j = 0; j < IPT; ++j) c += (cur[j] == 2);
        int incl = c;
        #pragma unroll
        for (int d = 1; d < 64; d <<= 1) {
            int n = __shfl_up(incl, d, 64);
            if (lane >= d) incl += n;
        }
        if (lane == 63) s_wi[par][wid] = incl;
        __syncthreads();
        // WAR across iters is covered by the parity buffer; write(i+2) to the
        // same buffer happens after barrier(i+1), by which point reads(i) done.
        int wex = 0, btot = 0;
        #pragma unroll
        for (int w = 0; w < NW; ++w) {
            int t = s_wi[par][w];
            wex  += (w < wid) ? t : 0;
            btot += t;
        }
        int k = kc + wex + (incl - c);
        #pragma unroll
        for (int j = 0; j < IPT; ++j) {
            const int s = cur[j];
            k += (s == 2);
            const float sp = (s == 0) ? sp0 : ((s == 1) ? sp1 : 0.f);
            const float* e = er + (size_t)k * 3;    // k <= T: in bounds
            vx += e[0] * sp; vy += e[1] * sp; vz += e[2] * sp;
        }
        kc += btot;
    }

    // block reduce (vx,vy,vz)
    #pragma unroll
    for (int d = 32; d > 0; d >>= 1) {
        vx += __shfl_down(vx, d, 64);
        vy += __shfl_down(vy, d, 64);
        vz += __shfl_down(vz, d, 64);
    }
    if (lane == 0) { s_wf[wid][0] = vx; s_wf[wid][1] = vy; s_wf[wid][2] = vz; }
    __syncthreads();
    if (tid == 0) {
        float tx = 0.f, ty = 0.f, tz = 0.f;
        #pragma unroll
        for (int w = 0; w < NW; ++w) {
            tx += s_wf[w][0]; ty += s_wf[w][1]; tz += s_wf[w][2];
        }
        float* o = velws + (size_t)blk * 3;   // unscaled vel sum (no dt)
        o[0] = tx; o[1] = ty; o[2] = tz;
    }
}

// ---------------- K3: positions (R2 verified chunk-scan, per partition) -------
__global__ __launch_bounds__(NT)
void traj_kernel(const int*   __restrict__ states,   // (B,T)
                 const float* __restrict__ e0s,      // (B,T+1,3)
                 const float* __restrict__ sp0v,     // (B,)
                 const float* __restrict__ sp1v,     // (B,)
                 const float* __restrict__ x0,       // (B,3)
                 float*       __restrict__ X,        // (B,T,3)
                 int T, int psz, int npart,
                 const int*   __restrict__ cnt,      // (B,npart) or null if npart==1
                 const float* __restrict__ velws)    // (B,npart,3) or null
{
    const int blk  = blockIdx.x;
    const int b    = blk / npart;
    const int p    = blk - b * npart;
    const int tid  = threadIdx.x;
    const int lane = tid & 63;
    const int wid  = tid >> 6;

    __shared__ int   s_wi[NW];
    __shared__ float s_wf[NW][3];

    const int*   st = states + (size_t)b * T;
    const float* er = e0s    + (size_t)b * (T + 1) * 3;
    float*       xr = X      + (size_t)b * T * 3;
    const float sp0 = sp0v[b], sp1 = sp1v[b];
    const float x00 = x0[3 * b + 0], x01 = x0[3 * b + 1], x02 = x0[3 * b + 2];

    const int pstart = p * psz;
    int pend = pstart + psz; if (pend > T) pend = T;

    // carries seeded from prior partitions (p==0 reads nothing: null-safe)
    int   kc  = 0;
    float pcx = 0.f, pcy = 0.f, pcz = 0.f;
    for (int q = 0; q < p; ++q) {
        kc += cnt[b * npart + q];
        const float* v = velws + (size_t)(b * npart + q) * 3;
        pcx += v[0]; pcy += v[1]; pcz += v[2];
    }

    // float4 store path valid iff the partition's first element is 16B-aligned
    // (per-thread deltas are 96B, so alignment is block-uniform).
    const bool al16 = (((uintptr_t)(xr + (size_t)pstart * 3)) & 15) == 0;

    int cur[IPT];
    load_states(st, pend, pstart + tid * IPT, cur);

    for (int base = pstart; base < pend; base += CHUNK) {
        // ---- prefetch next chunk's states
        int nxt[IPT];
        const bool has_next = (base + CHUNK) < pend;   // wave-uniform
        if (has_next) load_states(st, pend, base + CHUNK + tid * IPT, nxt);

        // ---- tumble-count block scan
        int c = 0;
        #pragma unroll
        for (int j = 0; j < IPT; ++j) c += (cur[j] == 2);
        int incl = c;
        #pragma unroll
        for (int d = 1; d < 64; d <<= 1) {
            int n = __shfl_up(incl, d, 64);
            if (lane >= d) incl += n;
        }
        if (lane == 63) s_wi[wid] = incl;
        __syncthreads();                                   // barrier 1
        int wex = 0, btot = 0;
        #pragma unroll
        for (int w = 0; w < NW; ++w) {
            int t = s_wi[w];
            wex  += (w < wid) ? t : 0;
            btot += t;
        }
        int k = kc + wex + (incl - c);

        // ---- batched gathers
        float ex[IPT], ey[IPT], ez[IPT];
        #pragma unroll
        for (int j = 0; j < IPT; ++j) {
            const int s = cur[j];
            k += (s == 2);
            const float sp = (s == 0) ? sp0 : ((s == 1) ? sp1 : 0.f);
            const float* e = er + (size_t)k * 3;
            ex[j] = e[0] * sp;
            ey[j] = e[1] * sp;
            ez[j] = e[2] * sp;
        }

        // ---- thread-local inclusive prefix, in place
        float px = 0.f, py = 0.f, pz = 0.f;
        #pragma unroll
        for (int j = 0; j < IPT; ++j) {
            px += ex[j]; ex[j] = px;
            py += ey[j]; ey[j] = py;
            pz += ez[j]; ez[j] = pz;
        }

        // ---- block scan (float3) of thread totals
        float ix = px, iy = py, iz = pz;
        #pragma unroll
        for (int d = 1; d < 64; d <<= 1) {
            float nx = __shfl_up(ix, d, 64);
            float ny = __shfl_up(iy, d, 64);
            float nz = __shfl_up(iz, d, 64);
            if (lane >= d) { ix += nx; iy += ny; iz += nz; }
        }
        if (lane == 63) { s_wf[wid][0] = ix; s_wf[wid][1] = iy; s_wf[wid][2] = iz; }
        __syncthreads();                                   // barrier 2
        float wfx = 0.f, wfy = 0.f, wfz = 0.f, btx = 0.f, bty = 0.f, btz = 0.f;
        #pragma unroll
        for (int w = 0; w < NW; ++w) {
            float tx = s_wf[w][0], ty = s_wf[w][1], tz = s_wf[w][2];
            if (w < wid) { wfx += tx; wfy += ty; wfz += tz; }
            btx += tx; bty += ty; btz += tz;
        }
        const float bx = pcx + wfx + (ix - px);
        const float by = pcy + wfy + (iy - py);
        const float bz = pcz + wfz + (iz - pz);

        // ---- finalize + store (96 B contiguous/thread)
        #define FX(j) (x00 + (bx + ex[j]) * 0.1f)
        #define FY(j) (x01 + (by + ey[j]) * 0.1f)
        #define FZ(j) (x02 + (bz + ez[j]) * 0.1f)
        const int e0i = base + tid * IPT;
        if (al16 && e0i + IPT <= pend) {
            float4* d4 = (float4*)(xr + (size_t)e0i * 3);
            d4[0] = make_float4(FX(0), FY(0), FZ(0), FX(1));
            d4[1] = make_float4(FY(1), FZ(1), FX(2), FY(2));
            d4[2] = make_float4(FZ(2), FX(3), FY(3), FZ(3));
            d4[3] = make_float4(FX(4), FY(4), FZ(4), FX(5));
            d4[4] = make_float4(FY(5), FZ(5), FX(6), FY(6));
            d4[5] = make_float4(FZ(6), FX(7), FY(7), FZ(7));
        } else {
            #pragma unroll
            for (int j = 0; j < IPT; ++j)
                if (e0i + j < pend) {
                    float* d = xr + (size_t)(e0i + j) * 3;
                    d[0] = FX(j); d[1] = FY(j); d[2] = FZ(j);
                }
        }
        #undef FX
        #undef FY
        #undef FZ

        // ---- carries
        kc  += btot;
        pcx += btx; pcy += bty; pcz += btz;

        #pragma unroll
        for (int j = 0; j < IPT; ++j) cur[j] = nxt[j];
    }
}

extern "C" void kernel_launch(void* const* d_in, const int* in_sizes, int n_in,
                              void* d_out, int out_size, void* d_ws, size_t ws_size,
                              hipStream_t stream) {
    const int*   states = (const int*)  d_in[0];
    const float* e0s    = (const float*)d_in[1];
    const float* sp0    = (const float*)d_in[2];
    const float* sp1    = (const float*)d_in[3];
    const float* x0     = (const float*)d_in[4];
    float*       X      = (float*)d_out;

    const int B = in_sizes[2];            // speed_0 has one entry per particle
    const int T = in_sizes[0] / B;        // states is (B,T)

    const size_t need = (size_t)B * NPART * 16;   // cnt: B*P ints, vel: B*P*3 floats
    if (d_ws != nullptr && ws_size >= need) {
        // partition size: multiple of 8 so int4 state loads stay aligned
        const int psz = (((T + NPART - 1) / NPART) + 7) & ~7;
        int*   cnt = (int*)d_ws;
        float* vel = (float*)((char*)d_ws + (size_t)B * NPART * 4);
        dim3 g(B * NPART), blk(NT);
        count_kernel <<<g, blk, 0, stream>>>(states, T, psz, NPART, cnt);
        velsum_kernel<<<g, blk, 0, stream>>>(states, e0s, sp0, sp1, T, psz, NPART,
                                             cnt, vel);
        traj_kernel  <<<g, blk, 0, stream>>>(states, e0s, sp0, sp1, x0, X, T, psz,
                                             NPART, cnt, vel);
    } else {
        // no workspace: single partition per particle (p==0 never touches ws)
        const int psz = (T + 7) & ~7;
        traj_kernel<<<dim3(B), dim3(NT), 0, stream>>>(states, e0s, sp0, sp1, x0, X,
                                                      T, psz, 1, nullptr, nullptr);
    }
}

// Round 4
// 612.607 us; speedup vs baseline: 1.0368x; 1.0368x over previous
//
#include <hip/hip_runtime.h>

// ThreeStateExplorer: B=256 particles, T=100k steps.
//   k[t]   = inclusive cumsum(states==2)
//   vel[t] = (states[t]==2 ? 0 : e0s[b,k[t]] * (states[t]==0 ? sp0 : sp1))
//   X[t]   = x0 + DT * cumsum(vel)
//
// R5 (resubmitted R6 — infra failed before execution, kernel never ran):
// single kernel (R4's 3-kernel split was neutral->worse: occupancy not the
// bottleneck; R3 showed barriers aren't either). This round attacks gather-
// transaction inflation: per chunk the block's k-window is only ~2731 rows
// (~33 KB) but direct per-element gathers issue ~11.5k line-requests per chunk
// per CU. Fix: stage the window [kc, kc+btot] into LDS with coalesced dword
// loads after the tumble scan (btot block-uniform), gather from LDS.
// Cap 4096 rows (48 KB, ~30 sigma above the Binomial(8192,1/3) mean); wave-
// uniform fallback to direct global gathers if ever exceeded.

#define NT      1024          // threads per block (16 waves)
#define IPT     8             // elements per thread per chunk
#define CHUNK   (NT * IPT)    // 8192
#define NW      (NT / 64)     // 16 waves
#define CAPROWS 4096          // LDS e0s-window capacity (rows of 3 floats)

__device__ __forceinline__ void load_states(const int* __restrict__ st, int lim,
                                            int e0i, int out[IPT]) {
    if (e0i + IPT <= lim) {
        int4 a = *(const int4*)(st + e0i);
        int4 b = *(const int4*)(st + e0i + 4);
        out[0] = a.x; out[1] = a.y; out[2] = a.z; out[3] = a.w;
        out[4] = b.x; out[5] = b.y; out[6] = b.z; out[7] = b.w;
    } else {
        #pragma unroll
        for (int j = 0; j < IPT; ++j)
            out[j] = (e0i + j < lim) ? st[e0i + j] : 3;  // sentinel: vel=0, no tumble
    }
}

__global__ __launch_bounds__(NT)
void traj_kernel(const int*   __restrict__ states,   // (B,T)
                 const float* __restrict__ e0s,      // (B,T+1,3)
                 const float* __restrict__ sp0v,     // (B,)
                 const float* __restrict__ sp1v,     // (B,)
                 const float* __restrict__ x0,       // (B,3)
                 float*       __restrict__ X,        // (B,T,3)
                 int T)
{
    const int b    = blockIdx.x;
    const int tid  = threadIdx.x;
    const int lane = tid & 63;
    const int wid  = tid >> 6;

    __shared__ float s_e[3 * CAPROWS];   // 48 KB e0s window
    __shared__ int   s_wi[NW];
    __shared__ float s_wf[NW][3];

    const int*   st = states + (size_t)b * T;
    const float* er = e0s    + (size_t)b * (T + 1) * 3;
    float*       xr = X      + (size_t)b * T * 3;
    const float sp0 = sp0v[b], sp1 = sp1v[b];
    const float x00 = x0[3 * b + 0], x01 = x0[3 * b + 1], x02 = x0[3 * b + 2];

    int   kc  = 0;                          // tumble-count carry
    float pcx = 0.f, pcy = 0.f, pcz = 0.f;  // position carry (un-scaled vel sum)

    int cur[IPT];
    load_states(st, T, tid * IPT, cur);

    for (int base = 0; base < T; base += CHUNK) {
        // ---- prefetch next chunk's states
        int nxt[IPT];
        const bool has_next = (base + CHUNK) < T;   // wave-uniform
        if (has_next) load_states(st, T, base + CHUNK + tid * IPT, nxt);

        // ---- tumble-count block scan
        int c = 0;
        #pragma unroll
        for (int j = 0; j < IPT; ++j) c += (cur[j] == 2);
        int incl = c;
        #pragma unroll
        for (int d = 1; d < 64; d <<= 1) {
            int n = __shfl_up(incl, d, 64);
            if (lane >= d) incl += n;
        }
        if (lane == 63) s_wi[wid] = incl;
        __syncthreads();                                   // barrier 1
        int wex = 0, btot = 0;
        #pragma unroll
        for (int w = 0; w < NW; ++w) {
            int t = s_wi[w];
            wex  += (w < wid) ? t : 0;
            btot += t;
        }
        int k = kc + wex + (incl - c);    // tumbles strictly before my 1st elem

        // ---- stage this chunk's e0s window [kc, kc+btot] into LDS (coalesced)
        // btot is block-uniform -> branch is uniform. Window rows = btot+1.
        const int  rows    = btot + 1;
        const bool use_lds = (rows <= CAPROWS);
        if (use_lds) {
            const float* ew = er + 3 * kc;       // 3*(kc+btot+1) <= 3*(T+1): in bounds
            const int n = 3 * rows;
            for (int idx = tid; idx < n; idx += NT) s_e[idx] = ew[idx];
        }
        __syncthreads();                                   // barrier S (window ready)
        // s_e hazards: prev chunk's s_e reads end before its barrier 2 < this B1
        // < these writes; next chunk's writes are after next B1 > this B2 > reads.

        // ---- gathers
        float ex[IPT], ey[IPT], ez[IPT];
        if (use_lds) {
            #pragma unroll
            for (int j = 0; j < IPT; ++j) {
                const int s = cur[j];
                k += (s == 2);                // inclusive count; sp=0 at tumble
                const float sp = (s == 0) ? sp0 : ((s == 1) ? sp1 : 0.f);
                const float* e = s_e + 3 * (k - kc);       // row offset in window
                ex[j] = e[0] * sp;
                ey[j] = e[1] * sp;
                ez[j] = e[2] * sp;
            }
        } else {
            #pragma unroll
            for (int j = 0; j < IPT; ++j) {
                const int s = cur[j];
                k += (s == 2);
                const float sp = (s == 0) ? sp0 : ((s == 1) ? sp1 : 0.f);
                const float* e = er + (size_t)k * 3;       // k <= T: in bounds
                ex[j] = e[0] * sp;
                ey[j] = e[1] * sp;
                ez[j] = e[2] * sp;
            }
        }

        // ---- thread-local inclusive prefix, in place
        float px = 0.f, py = 0.f, pz = 0.f;
        #pragma unroll
        for (int j = 0; j < IPT; ++j) {
            px += ex[j]; ex[j] = px;
            py += ey[j]; ey[j] = py;
            pz += ez[j]; ez[j] = pz;
        }

        // ---- block scan (float3) of thread totals
        float ix = px, iy = py, iz = pz;
        #pragma unroll
        for (int d = 1; d < 64; d <<= 1) {
            float nx = __shfl_up(ix, d, 64);
            float ny = __shfl_up(iy, d, 64);
            float nz = __shfl_up(iz, d, 64);
            if (lane >= d) { ix += nx; iy += ny; iz += nz; }
        }
        if (lane == 63) { s_wf[wid][0] = ix; s_wf[wid][1] = iy; s_wf[wid][2] = iz; }
        __syncthreads();                                   // barrier 2
        float wfx = 0.f, wfy = 0.f, wfz = 0.f, btx = 0.f, bty = 0.f, btz = 0.f;
        #pragma unroll
        for (int w = 0; w < NW; ++w) {
            float tx = s_wf[w][0], ty = s_wf[w][1], tz = s_wf[w][2];
            if (w < wid) { wfx += tx; wfy += ty; wfz += tz; }
            btx += tx; bty += ty; btz += tz;
        }
        const float bx = pcx + wfx + (ix - px);
        const float by = pcy + wfy + (iy - py);
        const float bz = pcz + wfz + (iz - pz);

        // ---- finalize + store (96 B contiguous/thread)
        #define FX(j) (x00 + (bx + ex[j]) * 0.1f)
        #define FY(j) (x01 + (by + ey[j]) * 0.1f)
        #define FZ(j) (x02 + (bz + ez[j]) * 0.1f)
        const int e0i = base + tid * IPT;
        if (e0i + IPT <= T) {
            float4* d4 = (float4*)(xr + (size_t)e0i * 3);  // 96 B offset: 16B-aligned
            d4[0] = make_float4(FX(0), FY(0), FZ(0), FX(1));
            d4[1] = make_float4(FY(1), FZ(1), FX(2), FY(2));
            d4[2] = make_float4(FZ(2), FX(3), FY(3), FZ(3));
            d4[3] = make_float4(FX(4), FY(4), FZ(4), FX(5));
            d4[4] = make_float4(FY(5), FZ(5), FX(6), FY(6));
            d4[5] = make_float4(FZ(6), FX(7), FY(7), FZ(7));
        } else {
            #pragma unroll
            for (int j = 0; j < IPT; ++j)
                if (e0i + j < T) {
                    float* d = xr + (size_t)(e0i + j) * 3;
                    d[0] = FX(j); d[1] = FY(j); d[2] = FZ(j);
                }
        }
        #undef FX
        #undef FY
        #undef FZ

        // ---- carries (uniform)
        kc  += btot;
        pcx += btx; pcy += bty; pcz += btz;

        #pragma unroll
        for (int j = 0; j < IPT; ++j) cur[j] = nxt[j];
    }
}

extern "C" void kernel_launch(void* const* d_in, const int* in_sizes, int n_in,
                              void* d_out, int out_size, void* d_ws, size_t ws_size,
                              hipStream_t stream) {
    const int*   states = (const int*)  d_in[0];
    const float* e0s    = (const float*)d_in[1];
    const float* sp0    = (const float*)d_in[2];
    const float* sp1    = (const float*)d_in[3];
    const float* x0     = (const float*)d_in[4];
    float*       X      = (float*)d_out;

    const int B = in_sizes[2];            // speed_0 has one entry per particle
    const int T = in_sizes[0] / B;        // states is (B,T)

    traj_kernel<<<dim3(B), dim3(NT), 0, stream>>>(states, e0s, sp0, sp1, x0, X, T);
}